// Round 11
// baseline (343.555 us; speedup 1.0000x reference)
//
#include <hip/hip_runtime.h>
#include <hip/hip_bf16.h>
#include <math.h>

#define N_NODES 10000
#define MPAD    10112    /* 79*128 */
#define N_EDGESI 120000
#define E_TOT   130000   /* with self loops */
#define F_INPUT 66
#define HEADS   10
#define F_HEAD  66
#define F_GAT   660      /* HEADS*F_HEAD */
#define F_GCN   1320
#define F_G1    1000
#define F_G2    64

typedef _Float16 half_t;
typedef __attribute__((ext_vector_type(2))) _Float16 f16x2;
typedef __attribute__((ext_vector_type(4))) _Float16 f16x4;
typedef __attribute__((ext_vector_type(8))) _Float16 f16x8;
typedef __attribute__((ext_vector_type(4))) float f32x4;

/* padded K / N for fp16 MFMA GEMMs (K mult of 64, N mult of 64) */
#define KP_GAT 128
#define NP_GAT 768
#define KP_GCN 704      /* = GAT output padded; also K of GCN GEMM */
#define NP_GCN 1408
#define KP_G1  1344
#define NP_G1  1024
#define KP_G2  1024
#define NP_G2  64

__device__ __forceinline__ float lky(float x, float s){ return x >= 0.f ? x : s*x; }

#if defined(__has_builtin)
#if __has_builtin(__builtin_amdgcn_global_load_lds)
#define HAVE_GLL 1
#endif
#endif

#ifdef HAVE_GLL
#define LDSLOAD16(g, l) __builtin_amdgcn_global_load_lds( \
    (const __attribute__((address_space(1))) void*)(g),   \
    (__attribute__((address_space(3))) void*)(l), 16, 0, 0)
#else
#define LDSLOAD16(g, l) (*(f16x8*)(l) = *(const f16x8*)(g))
#endif

/* ---------------- CSR build ---------------- */

__global__ void k_count(const int* __restrict__ ei, int* __restrict__ counts){
    int e = blockIdx.x*256 + threadIdx.x;
    if (e >= E_TOT) return;
    int dst = (e < N_EDGESI) ? ei[N_EDGESI + e] : (e - N_EDGESI);
    atomicAdd(&counts[dst], 1);
}

/* single-block scan, wave-shuffle based (proven r9/r10); dinv fused. */
__global__ __launch_bounds__(1024)
void k_scan(const int* __restrict__ counts, int* __restrict__ offsets,
            float* __restrict__ dinv){
    __shared__ int wsum[16];            /* 1024/64 waves */
    const int lane = threadIdx.x & 63;
    const int wave = threadIdx.x >> 6;
    int carry = 0;
    for (int base = 0; base < N_NODES; base += 1024){
        int i = base + threadIdx.x;
        int v = (i < N_NODES) ? counts[i] : 0;
        if (i < N_NODES) dinv[i] = rsqrtf(fmaxf((float)v, 1.0f));
        int x = v;
        #pragma unroll
        for (int off = 1; off < 64; off <<= 1){
            int y = __shfl_up(x, off, 64);
            if (lane >= off) x += y;
        }
        if (lane == 63) wsum[wave] = x;
        __syncthreads();
        if (wave == 0){
            int w = (lane < 16) ? wsum[lane] : 0;
            #pragma unroll
            for (int off = 1; off < 16; off <<= 1){
                int y = __shfl_up(w, off, 64);
                if (lane >= off) w += y;
            }
            if (lane < 16) wsum[lane] = w;
        }
        __syncthreads();
        int prefix = (wave > 0) ? wsum[wave-1] : 0;
        if (i < N_NODES) offsets[i] = carry + prefix + x - v;
        carry += wsum[15];
        __syncthreads();
    }
    if (threadIdx.x == 0) offsets[N_NODES] = carry;
}

__global__ void k_fill(const int* __restrict__ ei, const int* __restrict__ offsets,
                       int* __restrict__ cursor, int* __restrict__ src_sorted){
    int e = blockIdx.x*256 + threadIdx.x;
    if (e >= E_TOT) return;
    int s, d;
    if (e < N_EDGESI){ s = ei[e]; d = ei[N_EDGESI + e]; }
    else { s = e - N_EDGESI; d = s; }
    int pos = offsets[d] + atomicAdd(&cursor[d], 1);
    src_sorted[pos] = s;
}

/* ------- fused packer: blockIdx.y selects target; each slice is the proven
   k_xh / k_wt body with its own compile-time constants. 4 elems/thread. --- */

#define C_XH   (MPAD*KP_GAT)
#define C_WGAT (NP_GAT*KP_GAT)
#define C_WGCN (NP_GCN*KP_GCN)
#define C_WG1  (NP_G1*KP_G1)
#define C_WG2  (NP_G2*KP_G2)
#define PACK_BX ((C_WG1 + 1023) / 1024)   /* 1344 blocks, 1024 elems each */

__global__ void k_packy(const float* __restrict__ x,
                        const float* __restrict__ Wgat, const float* __restrict__ Wgcn,
                        const float* __restrict__ Wg1,  const float* __restrict__ Wg2,
                        half_t* __restrict__ xh, half_t* __restrict__ WgatT,
                        half_t* __restrict__ WgcnT, half_t* __restrict__ Wg1T,
                        half_t* __restrict__ Wg2T){
    int base = blockIdx.x*1024 + threadIdx.x;
    int y = blockIdx.y;
    #pragma unroll
    for (int p = 0; p < 4; p++){
        int idx = base + p*256;
        if (y == 0){
            if (idx < C_XH){
                int r = idx >> 7, c = idx & 127;
                xh[idx] = (half_t)((r < N_NODES && c < F_INPUT) ? x[r*F_INPUT + c] : 0.f);
            }
        } else if (y == 1){
            if (idx < C_WGAT){
                int n = idx >> 7, k = idx & 127;
                WgatT[idx] = (half_t)((n < F_GAT && k < F_INPUT) ? Wgat[k*F_GAT + n] : 0.f);
            }
        } else if (y == 2){
            if (idx < C_WGCN){
                int n = idx / KP_GCN, k = idx - n*KP_GCN;
                WgcnT[idx] = (half_t)((n < F_GCN && k < F_GAT) ? Wgcn[k*F_GCN + n] : 0.f);
            }
        } else if (y == 3){
            if (idx < C_WG1){
                int n = idx / KP_G1, k = idx - n*KP_G1;
                Wg1T[idx] = (half_t)((n < F_G1 && k < F_GCN) ? Wg1[k*F_G1 + n] : 0.f);
            }
        } else {
            if (idx < C_WG2){
                int n = idx >> 10, k = idx & 1023;
                Wg2T[idx] = (half_t)((n < F_G2 && k < F_G1) ? Wg2[k*F_G2 + n] : 0.f);
            }
        }
    }
}

/* ---------------- fp16 MFMA GEMM (128x64 tile, BK=64, XOR swizzle, XCD remap) */
__global__ __launch_bounds__(256)
void k_hgemm(const half_t* __restrict__ A, const half_t* __restrict__ Bt,
             half_t* __restrict__ C, const float* __restrict__ bias,
             int Nreal, int ldc, int Kp, float slope){
    __shared__ half_t As[128*64];
    __shared__ half_t Bs[64*64];
    const int tid = threadIdx.x;
    const int l = tid & 63;
    const int wid = tid >> 6;
    const int wr = wid >> 1, wc = wid & 1;

    const int gx = gridDim.x;
    const int nwg = gx * gridDim.y;
    const int orig = blockIdx.y * gx + blockIdx.x;
    const int q = nwg >> 3, r8 = nwg & 7;
    const int xcd = orig & 7, lin = orig >> 3;
    const int wgid = (xcd < r8 ? xcd*(q+1) : r8*(q+1) + (xcd-r8)*q) + lin;
    const int bx = wgid % gx, by = wgid / gx;

    const int brow = by * 128;
    const int bcol = bx * 64;

    f32x4 acc[4][2] = {};

    for (int k0 = 0; k0 < Kp; k0 += 64){
        #pragma unroll
        for (int i = 0; i < 4; i++){
            int s = tid + i*256;
            int row = s >> 3, chp = s & 7;
            int ch = chp ^ (row & 7);
            LDSLOAD16(A + (size_t)(brow+row)*Kp + k0 + ch*8, &As[s*8]);
        }
        #pragma unroll
        for (int i = 0; i < 2; i++){
            int s = tid + i*256;
            int row = s >> 3, chp = s & 7;
            int ch = chp ^ (row & 7);
            LDSLOAD16(Bt + (size_t)(bcol+row)*Kp + k0 + ch*8, &Bs[s*8]);
        }
        __syncthreads();
        #pragma unroll
        for (int t = 0; t < 2; t++){
            f16x8 af[4], bf[2];
            #pragma unroll
            for (int m = 0; m < 4; m++){
                int row = wr*64 + m*16 + (l & 15);
                int ch = (t*4 + (l >> 4)) ^ (row & 7);
                af[m] = *(const f16x8*)&As[row*64 + ch*8];
            }
            #pragma unroll
            for (int n = 0; n < 2; n++){
                int row = wc*32 + n*16 + (l & 15);
                int ch = (t*4 + (l >> 4)) ^ (row & 7);
                bf[n] = *(const f16x8*)&Bs[row*64 + ch*8];
            }
            #pragma unroll
            for (int m = 0; m < 4; m++)
                #pragma unroll
                for (int n = 0; n < 2; n++)
                    acc[m][n] = __builtin_amdgcn_mfma_f32_16x16x32_f16(
                        af[m], bf[n], acc[m][n], 0, 0, 0);
        }
        __syncthreads();
    }

    #pragma unroll
    for (int m = 0; m < 4; m++){
        #pragma unroll
        for (int n = 0; n < 2; n++){
            int col = bcol + wc*32 + n*16 + (l & 15);
            if (col >= ldc) continue;
            float bv = (bias && col < Nreal) ? bias[col] : 0.f;
            #pragma unroll
            for (int r = 0; r < 4; r++){
                int rowg = brow + wr*64 + m*16 + ((l >> 4) << 2) + r;
                float v = (col < Nreal) ? acc[m][n][r] + bv : 0.f;
                v = (v >= 0.f) ? v : slope*v;
                C[(size_t)rowg*ldc + col] = (half_t)v;
            }
        }
    }
}

/* ------- fused g2 GEMM + tail MLP. Grid (1, 79): each block owns 128 rows
   and ALL 64 g2 cols, so the tail (64->32->16->1) runs in-block from LDS. */
__global__ __launch_bounds__(256)
void k_g2tail(const half_t* __restrict__ A, const half_t* __restrict__ Bt,
              const float* __restrict__ bias,          /* b_g2 */
              const float* __restrict__ Wfc1, const float* __restrict__ bfc1,
              const float* __restrict__ Wfc2, const float* __restrict__ bfc2,
              const float* __restrict__ Wout, const float* __restrict__ bout,
              float* __restrict__ out){
    __shared__ half_t As[128*64];
    __shared__ half_t Bs[64*64];
    __shared__ float h4s[128][65];     /* +1 pad: bank-conflict-free row reads */
    __shared__ float W1s[64*32];
    __shared__ float W2s[32*16];
    __shared__ float Wos[16];
    __shared__ float b1s[32];
    __shared__ float b2s[16];
    const int tid = threadIdx.x;

    /* preload tail weights (overlaps with GEMM staging; h4s sync orders use) */
    for (int i = tid; i < 64*32; i += 256) W1s[i] = Wfc1[i];
    for (int i = tid; i < 32*16; i += 256) W2s[i] = Wfc2[i];
    if (tid < 16) Wos[tid] = Wout[tid];
    if (tid < 32) b1s[tid] = bfc1[tid];
    if (tid < 16) b2s[tid] = bfc2[tid];

    const int l = tid & 63;
    const int wid = tid >> 6;
    const int wr = wid >> 1, wc = wid & 1;

    /* XCD remap over the 79 y-blocks */
    const int nwg = gridDim.y;
    const int orig = blockIdx.y;
    const int q = nwg >> 3, r8 = nwg & 7;
    const int xcd = orig & 7, lin = orig >> 3;
    const int wgid = (xcd < r8 ? xcd*(q+1) : r8*(q+1) + (xcd-r8)*q) + lin;
    const int brow = wgid * 128;

    f32x4 acc[4][2] = {};

    for (int k0 = 0; k0 < KP_G2; k0 += 64){
        #pragma unroll
        for (int i = 0; i < 4; i++){
            int s = tid + i*256;
            int row = s >> 3, chp = s & 7;
            int ch = chp ^ (row & 7);
            LDSLOAD16(A + (size_t)(brow+row)*KP_G2 + k0 + ch*8, &As[s*8]);
        }
        #pragma unroll
        for (int i = 0; i < 2; i++){
            int s = tid + i*256;
            int row = s >> 3, chp = s & 7;
            int ch = chp ^ (row & 7);
            LDSLOAD16(Bt + (size_t)row*KP_G2 + k0 + ch*8, &Bs[s*8]);
        }
        __syncthreads();
        #pragma unroll
        for (int t = 0; t < 2; t++){
            f16x8 af[4], bf[2];
            #pragma unroll
            for (int m = 0; m < 4; m++){
                int row = wr*64 + m*16 + (l & 15);
                int ch = (t*4 + (l >> 4)) ^ (row & 7);
                af[m] = *(const f16x8*)&As[row*64 + ch*8];
            }
            #pragma unroll
            for (int n = 0; n < 2; n++){
                int row = wc*32 + n*16 + (l & 15);
                int ch = (t*4 + (l >> 4)) ^ (row & 7);
                bf[n] = *(const f16x8*)&Bs[row*64 + ch*8];
            }
            #pragma unroll
            for (int m = 0; m < 4; m++)
                #pragma unroll
                for (int n = 0; n < 2; n++)
                    acc[m][n] = __builtin_amdgcn_mfma_f32_16x16x32_f16(
                        af[m], bf[n], acc[m][n], 0, 0, 0);
        }
        __syncthreads();
    }

    /* epilogue: bias + leaky -> LDS tile (fp32, no global round-trip) */
    #pragma unroll
    for (int m = 0; m < 4; m++){
        #pragma unroll
        for (int n = 0; n < 2; n++){
            int col = wc*32 + n*16 + (l & 15);
            float bv = bias[col];
            #pragma unroll
            for (int r = 0; r < 4; r++){
                int row = wr*64 + m*16 + ((l >> 4) << 2) + r;
                float v = acc[m][n][r] + bv;
                h4s[row][col] = (v >= 0.f) ? v : 0.01f*v;
            }
        }
    }
    __syncthreads();

    /* tail MLP: one thread per row; W-reads are uniform (LDS broadcast) */
    if (tid < 128){
        int node = brow + tid;
        float h1v[32];
        #pragma unroll 4
        for (int j = 0; j < 32; j++){
            float a = b1s[j];
            #pragma unroll 8
            for (int i = 0; i < 64; i++) a += h4s[tid][i]*W1s[i*32 + j];
            h1v[j] = lky(a, 0.01f);
        }
        float h2v[16];
        #pragma unroll
        for (int j = 0; j < 16; j++){
            float a = b2s[j];
            #pragma unroll
            for (int i = 0; i < 32; i++) a += h1v[i]*W2s[i*16 + j];
            h2v[j] = lky(a, 0.01f);
        }
        float a3 = bout[0];
        #pragma unroll
        for (int i = 0; i < 16; i++) a3 += h2v[i]*Wos[i];
        if (node < N_NODES) out[node] = a3;
    }
}

/* ---------------- GAT attention ---------------- */

__global__ void k_attn_ad(const half_t* __restrict__ xt,
                          const float* __restrict__ att_src, const float* __restrict__ att_dst,
                          float* __restrict__ a_s, float* __restrict__ a_d){
    int t = blockIdx.x*256 + threadIdx.x;
    if (t >= N_NODES*HEADS) return;
    int n = t / HEADS, h = t - (t/HEADS)*HEADS;
    const half_t* xr = xt + (size_t)n*NP_GAT + h*F_HEAD;
    const float* as = att_src + h*F_HEAD;
    const float* ad = att_dst + h*F_HEAD;
    float s = 0.f, d = 0.f;
    #pragma unroll
    for (int f = 0; f < F_HEAD; f += 2){
        f16x2 v = *(const f16x2*)(xr + f);
        float vx = (float)v.x, vy = (float)v.y;
        s += vx*as[f] + vy*as[f+1];
        d += vx*ad[f] + vy*ad[f+1];
    }
    a_s[t] = s; a_d[t] = d;
}

/* fused edge-score + segment softmax: one thread per (node, head) */
__global__ void k_softmax(const int* __restrict__ offsets, const int* __restrict__ src_sorted,
                          const float* __restrict__ a_s, const float* __restrict__ a_d,
                          float* __restrict__ e_sorted, float* __restrict__ inv_s){
    int t = blockIdx.x*256 + threadIdx.x;
    if (t >= N_NODES*HEADS) return;
    int n = t / HEADS, h = t - (t/HEADS)*HEADS;
    int b = offsets[n], e = offsets[n+1];
    float ad_n = a_d[t];
    float m = -INFINITY;
    for (int s = b; s < e; s++){
        float v = lky(a_s[src_sorted[s]*HEADS + h] + ad_n, 0.2f);
        e_sorted[(size_t)s*HEADS + h] = v;
        m = fmaxf(m, v);
    }
    float sum = 0.f;
    for (int s = b; s < e; s++){
        float ex = __expf(e_sorted[(size_t)s*HEADS + h] - m);
        e_sorted[(size_t)s*HEADS + h] = ex;
        sum += ex;
    }
    inv_s[t] = 1.0f / fmaxf(sum, 1e-16f);
}

/* GAT aggregation: block(192) per node, f16x4 per thread, edge loop x4 */
__global__ __launch_bounds__(192)
void k_gat_agg(const int* __restrict__ offsets, const int* __restrict__ src_sorted,
               const float* __restrict__ e_sorted, const float* __restrict__ inv_s,
               const half_t* __restrict__ xt, const float* __restrict__ b_gat,
               half_t* __restrict__ out){
    int n = blockIdx.x, t = threadIdx.x;
    int f0 = 4*t;
    if (t < 165){
        int h0 = f0/F_HEAD;
        int h1 = (f0+1)/F_HEAD;
        int h2 = (f0+2)/F_HEAD;
        int h3 = (f0+3)/F_HEAD;
        int b = offsets[n], e = offsets[n+1];
        float a0=0.f, a1=0.f, a2=0.f, a3=0.f;
        int s = b;
        for (; s + 4 <= e; s += 4){
            int s0 = src_sorted[s],   s1 = src_sorted[s+1];
            int s2 = src_sorted[s+2], s3 = src_sorted[s+3];
            f16x4 v0 = *(const f16x4*)(xt + (size_t)s0*NP_GAT + f0);
            f16x4 v1 = *(const f16x4*)(xt + (size_t)s1*NP_GAT + f0);
            f16x4 v2 = *(const f16x4*)(xt + (size_t)s2*NP_GAT + f0);
            f16x4 v3 = *(const f16x4*)(xt + (size_t)s3*NP_GAT + f0);
            const float* e0 = e_sorted + (size_t)s*HEADS;
            const float* e1 = e0 + HEADS;
            const float* e2 = e0 + 2*HEADS;
            const float* e3 = e0 + 3*HEADS;
            a0 += e0[h0]*(float)v0.x + e1[h0]*(float)v1.x + e2[h0]*(float)v2.x + e3[h0]*(float)v3.x;
            a1 += e0[h1]*(float)v0.y + e1[h1]*(float)v1.y + e2[h1]*(float)v2.y + e3[h1]*(float)v3.y;
            a2 += e0[h2]*(float)v0.z + e1[h2]*(float)v1.z + e2[h2]*(float)v2.z + e3[h2]*(float)v3.z;
            a3 += e0[h3]*(float)v0.w + e1[h3]*(float)v1.w + e2[h3]*(float)v2.w + e3[h3]*(float)v3.w;
        }
        for (; s < e; s++){
            int s0 = src_sorted[s];
            f16x4 v0 = *(const f16x4*)(xt + (size_t)s0*NP_GAT + f0);
            const float* e0 = e_sorted + (size_t)s*HEADS;
            a0 += e0[h0]*(float)v0.x;
            a1 += e0[h1]*(float)v0.y;
            a2 += e0[h2]*(float)v0.z;
            a3 += e0[h3]*(float)v0.w;
        }
        const float* iv = inv_s + n*HEADS;
        f16x4 r;
        r.x = (half_t)lky(a0*iv[h0] + b_gat[f0  ], 0.01f);
        r.y = (half_t)lky(a1*iv[h1] + b_gat[f0+1], 0.01f);
        r.z = (half_t)lky(a2*iv[h2] + b_gat[f0+2], 0.01f);
        r.w = (half_t)lky(a3*iv[h3] + b_gat[f0+3], 0.01f);
        *(f16x4*)(out + (size_t)n*KP_GCN + f0) = r;
    } else if (t < 176){
        f16x4 z = {(half_t)0.f,(half_t)0.f,(half_t)0.f,(half_t)0.f};
        *(f16x4*)(out + (size_t)n*KP_GCN + f0) = z;
    }
}

/* ---------------- GCN (aggregate-first) ---------------- */

__global__ __launch_bounds__(192)
void k_gcn_pre(const int* __restrict__ offsets, const int* __restrict__ src_sorted,
               const float* __restrict__ dinv, const half_t* __restrict__ h1,
               half_t* __restrict__ agg){
    int n = blockIdx.x, t = threadIdx.x;
    int f0 = 4*t;
    if (t < 165){
        int b = offsets[n], e = offsets[n+1];
        float a0=0.f, a1=0.f, a2=0.f, a3=0.f;
        int s = b;
        for (; s + 4 <= e; s += 4){
            int s0 = src_sorted[s],   s1 = src_sorted[s+1];
            int s2 = src_sorted[s+2], s3 = src_sorted[s+3];
            float n0 = dinv[s0], n1 = dinv[s1], n2 = dinv[s2], n3 = dinv[s3];
            f16x4 v0 = *(const f16x4*)(h1 + (size_t)s0*KP_GCN + f0);
            f16x4 v1 = *(const f16x4*)(h1 + (size_t)s1*KP_GCN + f0);
            f16x4 v2 = *(const f16x4*)(h1 + (size_t)s2*KP_GCN + f0);
            f16x4 v3 = *(const f16x4*)(h1 + (size_t)s3*KP_GCN + f0);
            a0 += n0*(float)v0.x + n1*(float)v1.x + n2*(float)v2.x + n3*(float)v3.x;
            a1 += n0*(float)v0.y + n1*(float)v1.y + n2*(float)v2.y + n3*(float)v3.y;
            a2 += n0*(float)v0.z + n1*(float)v1.z + n2*(float)v2.z + n3*(float)v3.z;
            a3 += n0*(float)v0.w + n1*(float)v1.w + n2*(float)v2.w + n3*(float)v3.w;
        }
        for (; s < e; s++){
            int s0 = src_sorted[s];
            float n0 = dinv[s0];
            f16x4 v0 = *(const f16x4*)(h1 + (size_t)s0*KP_GCN + f0);
            a0 += n0*(float)v0.x;
            a1 += n0*(float)v0.y;
            a2 += n0*(float)v0.z;
            a3 += n0*(float)v0.w;
        }
        float dn = dinv[n];
        f16x4 r;
        r.x = (half_t)(dn*a0); r.y = (half_t)(dn*a1);
        r.z = (half_t)(dn*a2); r.w = (half_t)(dn*a3);
        *(f16x4*)(agg + (size_t)n*KP_GCN + f0) = r;
    } else if (t < 176){
        f16x4 z = {(half_t)0.f,(half_t)0.f,(half_t)0.f,(half_t)0.f};
        *(f16x4*)(agg + (size_t)n*KP_GCN + f0) = z;
    }
}

/* ---------------- launch ---------------- */

extern "C" void kernel_launch(void* const* d_in, const int* in_sizes, int n_in,
                              void* d_out, int out_size, void* d_ws, size_t ws_size,
                              hipStream_t stream){
    const float* x       = (const float*)d_in[0];
    const int*   ei      = (const int*)  d_in[1];
    const float* W_gat   = (const float*)d_in[2];
    const float* att_src = (const float*)d_in[3];
    const float* att_dst = (const float*)d_in[4];
    const float* b_gat   = (const float*)d_in[5];
    const float* W_gcn   = (const float*)d_in[6];
    const float* b_gcn   = (const float*)d_in[7];
    const float* W_g1    = (const float*)d_in[8];
    const float* b_g1    = (const float*)d_in[9];
    const float* W_g2    = (const float*)d_in[10];
    const float* b_g2    = (const float*)d_in[11];
    const float* W_fc1   = (const float*)d_in[12];
    const float* b_fc1   = (const float*)d_in[13];
    const float* W_fc2   = (const float*)d_in[14];
    const float* b_fc2   = (const float*)d_in[15];
    const float* W_out   = (const float*)d_in[16];
    const float* b_out   = (const float*)d_in[17];
    float* out = (float*)d_out;
    char* ws = (char*)d_ws;

    size_t off = 0;
    auto alloc = [&](size_t bytes){ size_t o = off; off += (bytes + 255) & ~(size_t)255; return o; };
    size_t o_counts = alloc(N_NODES*4);
    size_t o_cursor = alloc(N_NODES*4);
    size_t o_offs   = alloc((N_NODES+1)*4);
    size_t o_as     = alloc(N_NODES*HEADS*4);
    size_t o_ad     = alloc(N_NODES*HEADS*4);
    size_t o_invs   = alloc(N_NODES*HEADS*4);
    size_t o_dinv   = alloc(N_NODES*4);
    size_t o_srcs   = alloc(E_TOT*4);
    size_t o_esrt   = alloc((size_t)E_TOT*HEADS*4);
    size_t o_xh     = alloc((size_t)MPAD*KP_GAT*2);
    size_t o_xt     = alloc((size_t)MPAD*NP_GAT*2);
    size_t o_h1     = alloc((size_t)N_NODES*KP_GCN*2);
    size_t o_agg    = alloc((size_t)MPAD*KP_GCN*2);
    size_t o_h2     = alloc((size_t)MPAD*KP_G1*2);
    size_t o_h3     = alloc((size_t)MPAD*KP_G2*2);
    size_t o_wgatT  = alloc((size_t)NP_GAT*KP_GAT*2);
    size_t o_wgcnT  = alloc((size_t)NP_GCN*KP_GCN*2);
    size_t o_wg1T   = alloc((size_t)NP_G1*KP_G1*2);
    size_t o_wg2T   = alloc((size_t)NP_G2*KP_G2*2);

    int*    counts  = (int*)(ws + o_counts);
    int*    cursor  = (int*)(ws + o_cursor);
    int*    offsets = (int*)(ws + o_offs);
    float*  a_s     = (float*)(ws + o_as);
    float*  a_d     = (float*)(ws + o_ad);
    float*  inv_s   = (float*)(ws + o_invs);
    float*  dinv    = (float*)(ws + o_dinv);
    int*    src_srt = (int*)(ws + o_srcs);
    float*  e_srt   = (float*)(ws + o_esrt);
    half_t* xh      = (half_t*)(ws + o_xh);
    half_t* xt_h    = (half_t*)(ws + o_xt);
    half_t* h1h     = (half_t*)(ws + o_h1);
    half_t* aggh    = (half_t*)(ws + o_agg);
    half_t* h2h     = (half_t*)(ws + o_h2);
    half_t* h3h     = (half_t*)(ws + o_h3);
    half_t* WgatT   = (half_t*)(ws + o_wgatT);
    half_t* WgcnT   = (half_t*)(ws + o_wgcnT);
    half_t* Wg1T    = (half_t*)(ws + o_wg1T);
    half_t* Wg2T    = (half_t*)(ws + o_wg2T);

    /* CSR build (counts+cursor adjacent: one memset covers both) */
    hipMemsetAsync(ws + o_counts, 0, o_offs - o_counts, stream);
    k_count<<<(E_TOT+255)/256, 256, 0, stream>>>(ei, counts);
    k_scan<<<1, 1024, 0, stream>>>(counts, offsets, dinv);
    k_fill<<<(E_TOT+255)/256, 256, 0, stream>>>(ei, offsets, cursor, src_srt);

    /* fused fp16 packing (one launch, y-sliced) */
    k_packy<<<dim3(PACK_BX, 5), 256, 0, stream>>>(x, W_gat, W_gcn, W_g1, W_g2,
                                                  xh, WgatT, WgcnT, Wg1T, Wg2T);

    /* GAT: xt = x @ W_gat */
    k_hgemm<<<dim3(NP_GAT/64, MPAD/128), 256, 0, stream>>>(
        xh, WgatT, xt_h, nullptr, F_GAT, NP_GAT, KP_GAT, 1.0f);
    k_attn_ad<<<(N_NODES*HEADS+255)/256, 256, 0, stream>>>(xt_h, att_src, att_dst, a_s, a_d);
    k_softmax<<<(N_NODES*HEADS+255)/256, 256, 0, stream>>>(offsets, src_srt, a_s, a_d, e_srt, inv_s);
    k_gat_agg<<<N_NODES, 192, 0, stream>>>(offsets, src_srt, e_srt, inv_s, xt_h, b_gat, h1h);

    /* GCN aggregate-first */
    k_gcn_pre<<<N_NODES, 192, 0, stream>>>(offsets, src_srt, dinv, h1h, aggh);
    k_hgemm<<<dim3(NP_GCN/64, MPAD/128), 256, 0, stream>>>(
        aggh, WgcnT, h2h, b_gcn, F_GCN, KP_G1, KP_GCN, 0.01f);

    /* dense tail: g1 GEMM, then fused g2+MLP */
    k_hgemm<<<dim3(NP_G1/64, MPAD/128), 256, 0, stream>>>(
        h2h, Wg1T, h3h, b_g1, F_G1, KP_G2, KP_G1, 0.01f);
    k_g2tail<<<dim3(1, MPAD/128), 256, 0, stream>>>(
        h3h, Wg2T, b_g2, W_fc1, b_fc1, W_fc2, b_fc2, W_out, b_out, out);
}

// Round 12
// 330.704 us; speedup vs baseline: 1.0389x; 1.0389x over previous
//
#include <hip/hip_runtime.h>
#include <hip/hip_bf16.h>
#include <math.h>

#define N_NODES 10000
#define MPAD    10112    /* 79*128 */
#define N_EDGESI 120000
#define E_TOT   130000   /* with self loops */
#define F_INPUT 66
#define HEADS   10
#define F_HEAD  66
#define F_GAT   660      /* HEADS*F_HEAD */
#define F_GCN   1320
#define F_G1    1000
#define F_G2    64

typedef _Float16 half_t;
typedef __attribute__((ext_vector_type(2))) _Float16 f16x2;
typedef __attribute__((ext_vector_type(4))) _Float16 f16x4;
typedef __attribute__((ext_vector_type(8))) _Float16 f16x8;
typedef __attribute__((ext_vector_type(4))) float f32x4;

/* padded K / N for fp16 MFMA GEMMs (K mult of 64, N mult of 64) */
#define KP_GAT 128
#define NP_GAT 768
#define KP_GCN 704      /* = GAT output padded; also K of GCN GEMM */
#define NP_GCN 1408
#define KP_G1  1344
#define NP_G1  1024
#define KP_G2  1024
#define NP_G2  64

__device__ __forceinline__ float lky(float x, float s){ return x >= 0.f ? x : s*x; }

#if defined(__has_builtin)
#if __has_builtin(__builtin_amdgcn_global_load_lds)
#define HAVE_GLL 1
#endif
#endif

#ifdef HAVE_GLL
#define LDSLOAD16(g, l) __builtin_amdgcn_global_load_lds( \
    (const __attribute__((address_space(1))) void*)(g),   \
    (__attribute__((address_space(3))) void*)(l), 16, 0, 0)
#else
#define LDSLOAD16(g, l) (*(f16x8*)(l) = *(const f16x8*)(g))
#endif

/* ---------------- CSR build ---------------- */

__global__ void k_count(const int* __restrict__ ei, int* __restrict__ counts){
    int e = blockIdx.x*256 + threadIdx.x;
    if (e >= E_TOT) return;
    int dst = (e < N_EDGESI) ? ei[N_EDGESI + e] : (e - N_EDGESI);
    atomicAdd(&counts[dst], 1);
}

/* single-block scan, wave-shuffle based (proven r9/r10); dinv fused. */
__global__ __launch_bounds__(1024)
void k_scan(const int* __restrict__ counts, int* __restrict__ offsets,
            float* __restrict__ dinv){
    __shared__ int wsum[16];            /* 1024/64 waves */
    const int lane = threadIdx.x & 63;
    const int wave = threadIdx.x >> 6;
    int carry = 0;
    for (int base = 0; base < N_NODES; base += 1024){
        int i = base + threadIdx.x;
        int v = (i < N_NODES) ? counts[i] : 0;
        if (i < N_NODES) dinv[i] = rsqrtf(fmaxf((float)v, 1.0f));
        int x = v;
        #pragma unroll
        for (int off = 1; off < 64; off <<= 1){
            int y = __shfl_up(x, off, 64);
            if (lane >= off) x += y;
        }
        if (lane == 63) wsum[wave] = x;
        __syncthreads();
        if (wave == 0){
            int w = (lane < 16) ? wsum[lane] : 0;
            #pragma unroll
            for (int off = 1; off < 16; off <<= 1){
                int y = __shfl_up(w, off, 64);
                if (lane >= off) w += y;
            }
            if (lane < 16) wsum[lane] = w;
        }
        __syncthreads();
        int prefix = (wave > 0) ? wsum[wave-1] : 0;
        if (i < N_NODES) offsets[i] = carry + prefix + x - v;
        carry += wsum[15];
        __syncthreads();
    }
    if (threadIdx.x == 0) offsets[N_NODES] = carry;
}

__global__ void k_fill(const int* __restrict__ ei, const int* __restrict__ offsets,
                       int* __restrict__ cursor, int* __restrict__ src_sorted){
    int e = blockIdx.x*256 + threadIdx.x;
    if (e >= E_TOT) return;
    int s, d;
    if (e < N_EDGESI){ s = ei[e]; d = ei[N_EDGESI + e]; }
    else { s = e - N_EDGESI; d = s; }
    int pos = offsets[d] + atomicAdd(&cursor[d], 1);
    src_sorted[pos] = s;
}

/* ------- fused packer: blockIdx.y selects target; each slice is the proven
   k_xh / k_wt body with its own compile-time constants. 4 elems/thread. --- */

#define C_XH   (MPAD*KP_GAT)
#define C_WGAT (NP_GAT*KP_GAT)
#define C_WGCN (NP_GCN*KP_GCN)
#define C_WG1  (NP_G1*KP_G1)
#define C_WG2  (NP_G2*KP_G2)
#define PACK_BX ((C_WG1 + 1023) / 1024)   /* 1344 blocks, 1024 elems each */

__global__ void k_packy(const float* __restrict__ x,
                        const float* __restrict__ Wgat, const float* __restrict__ Wgcn,
                        const float* __restrict__ Wg1,  const float* __restrict__ Wg2,
                        half_t* __restrict__ xh, half_t* __restrict__ WgatT,
                        half_t* __restrict__ WgcnT, half_t* __restrict__ Wg1T,
                        half_t* __restrict__ Wg2T){
    int base = blockIdx.x*1024 + threadIdx.x;
    int y = blockIdx.y;
    #pragma unroll
    for (int p = 0; p < 4; p++){
        int idx = base + p*256;
        if (y == 0){
            if (idx < C_XH){
                int r = idx >> 7, c = idx & 127;
                xh[idx] = (half_t)((r < N_NODES && c < F_INPUT) ? x[r*F_INPUT + c] : 0.f);
            }
        } else if (y == 1){
            if (idx < C_WGAT){
                int n = idx >> 7, k = idx & 127;
                WgatT[idx] = (half_t)((n < F_GAT && k < F_INPUT) ? Wgat[k*F_GAT + n] : 0.f);
            }
        } else if (y == 2){
            if (idx < C_WGCN){
                int n = idx / KP_GCN, k = idx - n*KP_GCN;
                WgcnT[idx] = (half_t)((n < F_GCN && k < F_GAT) ? Wgcn[k*F_GCN + n] : 0.f);
            }
        } else if (y == 3){
            if (idx < C_WG1){
                int n = idx / KP_G1, k = idx - n*KP_G1;
                Wg1T[idx] = (half_t)((n < F_G1 && k < F_GCN) ? Wg1[k*F_G1 + n] : 0.f);
            }
        } else {
            if (idx < C_WG2){
                int n = idx >> 10, k = idx & 1023;
                Wg2T[idx] = (half_t)((n < F_G2 && k < F_G1) ? Wg2[k*F_G2 + n] : 0.f);
            }
        }
    }
}

/* ---------------- fp16 MFMA GEMM (128x64 tile, BK=64, XOR swizzle, XCD remap) */
__global__ __launch_bounds__(256)
void k_hgemm(const half_t* __restrict__ A, const half_t* __restrict__ Bt,
             half_t* __restrict__ C, const float* __restrict__ bias,
             int Nreal, int ldc, int Kp, float slope){
    __shared__ half_t As[128*64];
    __shared__ half_t Bs[64*64];
    const int tid = threadIdx.x;
    const int l = tid & 63;
    const int wid = tid >> 6;
    const int wr = wid >> 1, wc = wid & 1;

    const int gx = gridDim.x;
    const int nwg = gx * gridDim.y;
    const int orig = blockIdx.y * gx + blockIdx.x;
    const int q = nwg >> 3, r8 = nwg & 7;
    const int xcd = orig & 7, lin = orig >> 3;
    const int wgid = (xcd < r8 ? xcd*(q+1) : r8*(q+1) + (xcd-r8)*q) + lin;
    const int bx = wgid % gx, by = wgid / gx;

    const int brow = by * 128;
    const int bcol = bx * 64;

    f32x4 acc[4][2] = {};

    for (int k0 = 0; k0 < Kp; k0 += 64){
        #pragma unroll
        for (int i = 0; i < 4; i++){
            int s = tid + i*256;
            int row = s >> 3, chp = s & 7;
            int ch = chp ^ (row & 7);
            LDSLOAD16(A + (size_t)(brow+row)*Kp + k0 + ch*8, &As[s*8]);
        }
        #pragma unroll
        for (int i = 0; i < 2; i++){
            int s = tid + i*256;
            int row = s >> 3, chp = s & 7;
            int ch = chp ^ (row & 7);
            LDSLOAD16(Bt + (size_t)(bcol+row)*Kp + k0 + ch*8, &Bs[s*8]);
        }
        __syncthreads();
        #pragma unroll
        for (int t = 0; t < 2; t++){
            f16x8 af[4], bf[2];
            #pragma unroll
            for (int m = 0; m < 4; m++){
                int row = wr*64 + m*16 + (l & 15);
                int ch = (t*4 + (l >> 4)) ^ (row & 7);
                af[m] = *(const f16x8*)&As[row*64 + ch*8];
            }
            #pragma unroll
            for (int n = 0; n < 2; n++){
                int row = wc*32 + n*16 + (l & 15);
                int ch = (t*4 + (l >> 4)) ^ (row & 7);
                bf[n] = *(const f16x8*)&Bs[row*64 + ch*8];
            }
            #pragma unroll
            for (int m = 0; m < 4; m++)
                #pragma unroll
                for (int n = 0; n < 2; n++)
                    acc[m][n] = __builtin_amdgcn_mfma_f32_16x16x32_f16(
                        af[m], bf[n], acc[m][n], 0, 0, 0);
        }
        __syncthreads();
    }

    #pragma unroll
    for (int m = 0; m < 4; m++){
        #pragma unroll
        for (int n = 0; n < 2; n++){
            int col = bcol + wc*32 + n*16 + (l & 15);
            if (col >= ldc) continue;
            float bv = (bias && col < Nreal) ? bias[col] : 0.f;
            #pragma unroll
            for (int r = 0; r < 4; r++){
                int rowg = brow + wr*64 + m*16 + ((l >> 4) << 2) + r;
                float v = (col < Nreal) ? acc[m][n][r] + bv : 0.f;
                v = (v >= 0.f) ? v : slope*v;
                C[(size_t)rowg*ldc + col] = (half_t)v;
            }
        }
    }
}

/* ---------------- GAT attention ---------------- */

__global__ void k_attn_ad(const half_t* __restrict__ xt,
                          const float* __restrict__ att_src, const float* __restrict__ att_dst,
                          float* __restrict__ a_s, float* __restrict__ a_d){
    int t = blockIdx.x*256 + threadIdx.x;
    if (t >= N_NODES*HEADS) return;
    int n = t / HEADS, h = t - (t/HEADS)*HEADS;
    const half_t* xr = xt + (size_t)n*NP_GAT + h*F_HEAD;
    const float* as = att_src + h*F_HEAD;
    const float* ad = att_dst + h*F_HEAD;
    float s = 0.f, d = 0.f;
    #pragma unroll
    for (int f = 0; f < F_HEAD; f += 2){
        f16x2 v = *(const f16x2*)(xr + f);
        float vx = (float)v.x, vy = (float)v.y;
        s += vx*as[f] + vy*as[f+1];
        d += vx*ad[f] + vy*ad[f+1];
    }
    a_s[t] = s; a_d[t] = d;
}

/* fused edge-score + segment softmax: one thread per (node, head) */
__global__ void k_softmax(const int* __restrict__ offsets, const int* __restrict__ src_sorted,
                          const float* __restrict__ a_s, const float* __restrict__ a_d,
                          float* __restrict__ e_sorted, float* __restrict__ inv_s){
    int t = blockIdx.x*256 + threadIdx.x;
    if (t >= N_NODES*HEADS) return;
    int n = t / HEADS, h = t - (t/HEADS)*HEADS;
    int b = offsets[n], e = offsets[n+1];
    float ad_n = a_d[t];
    float m = -INFINITY;
    for (int s = b; s < e; s++){
        float v = lky(a_s[src_sorted[s]*HEADS + h] + ad_n, 0.2f);
        e_sorted[(size_t)s*HEADS + h] = v;
        m = fmaxf(m, v);
    }
    float sum = 0.f;
    for (int s = b; s < e; s++){
        float ex = __expf(e_sorted[(size_t)s*HEADS + h] - m);
        e_sorted[(size_t)s*HEADS + h] = ex;
        sum += ex;
    }
    inv_s[t] = 1.0f / fmaxf(sum, 1e-16f);
}

/* GAT aggregation: block(192) per node, f16x4 per thread, edge loop x4.
   Threads <165 cover the 660 REAL columns only; 165..175 write pad. */
__global__ __launch_bounds__(192)
void k_gat_agg(const int* __restrict__ offsets, const int* __restrict__ src_sorted,
               const float* __restrict__ e_sorted, const float* __restrict__ inv_s,
               const half_t* __restrict__ xt, const float* __restrict__ b_gat,
               half_t* __restrict__ out){
    int n = blockIdx.x, t = threadIdx.x;
    int f0 = 4*t;
    if (t < 165){
        int h0 = f0/F_HEAD;
        int h1 = (f0+1)/F_HEAD;
        int h2 = (f0+2)/F_HEAD;
        int h3 = (f0+3)/F_HEAD;
        int b = offsets[n], e = offsets[n+1];
        float a0=0.f, a1=0.f, a2=0.f, a3=0.f;
        int s = b;
        for (; s + 4 <= e; s += 4){
            int s0 = src_sorted[s],   s1 = src_sorted[s+1];
            int s2 = src_sorted[s+2], s3 = src_sorted[s+3];
            f16x4 v0 = *(const f16x4*)(xt + (size_t)s0*NP_GAT + f0);
            f16x4 v1 = *(const f16x4*)(xt + (size_t)s1*NP_GAT + f0);
            f16x4 v2 = *(const f16x4*)(xt + (size_t)s2*NP_GAT + f0);
            f16x4 v3 = *(const f16x4*)(xt + (size_t)s3*NP_GAT + f0);
            const float* e0 = e_sorted + (size_t)s*HEADS;
            const float* e1 = e0 + HEADS;
            const float* e2 = e0 + 2*HEADS;
            const float* e3 = e0 + 3*HEADS;
            a0 += e0[h0]*(float)v0.x + e1[h0]*(float)v1.x + e2[h0]*(float)v2.x + e3[h0]*(float)v3.x;
            a1 += e0[h1]*(float)v0.y + e1[h1]*(float)v1.y + e2[h1]*(float)v2.y + e3[h1]*(float)v3.y;
            a2 += e0[h2]*(float)v0.z + e1[h2]*(float)v1.z + e2[h2]*(float)v2.z + e3[h2]*(float)v3.z;
            a3 += e0[h3]*(float)v0.w + e1[h3]*(float)v1.w + e2[h3]*(float)v2.w + e3[h3]*(float)v3.w;
        }
        for (; s < e; s++){
            int s0 = src_sorted[s];
            f16x4 v0 = *(const f16x4*)(xt + (size_t)s0*NP_GAT + f0);
            const float* e0 = e_sorted + (size_t)s*HEADS;
            a0 += e0[h0]*(float)v0.x;
            a1 += e0[h1]*(float)v0.y;
            a2 += e0[h2]*(float)v0.z;
            a3 += e0[h3]*(float)v0.w;
        }
        const float* iv = inv_s + n*HEADS;
        f16x4 r;
        r.x = (half_t)lky(a0*iv[h0] + b_gat[f0  ], 0.01f);
        r.y = (half_t)lky(a1*iv[h1] + b_gat[f0+1], 0.01f);
        r.z = (half_t)lky(a2*iv[h2] + b_gat[f0+2], 0.01f);
        r.w = (half_t)lky(a3*iv[h3] + b_gat[f0+3], 0.01f);
        *(f16x4*)(out + (size_t)n*KP_GCN + f0) = r;
    } else if (t < 176){
        f16x4 z = {(half_t)0.f,(half_t)0.f,(half_t)0.f,(half_t)0.f};
        *(f16x4*)(out + (size_t)n*KP_GCN + f0) = z;
    }
}

/* ---------------- GCN (aggregate-first) ---------------- */

__global__ __launch_bounds__(192)
void k_gcn_pre(const int* __restrict__ offsets, const int* __restrict__ src_sorted,
               const float* __restrict__ dinv, const half_t* __restrict__ h1,
               half_t* __restrict__ agg){
    int n = blockIdx.x, t = threadIdx.x;
    int f0 = 4*t;
    if (t < 165){
        int b = offsets[n], e = offsets[n+1];
        float a0=0.f, a1=0.f, a2=0.f, a3=0.f;
        int s = b;
        for (; s + 4 <= e; s += 4){
            int s0 = src_sorted[s],   s1 = src_sorted[s+1];
            int s2 = src_sorted[s+2], s3 = src_sorted[s+3];
            float n0 = dinv[s0], n1 = dinv[s1], n2 = dinv[s2], n3 = dinv[s3];
            f16x4 v0 = *(const f16x4*)(h1 + (size_t)s0*KP_GCN + f0);
            f16x4 v1 = *(const f16x4*)(h1 + (size_t)s1*KP_GCN + f0);
            f16x4 v2 = *(const f16x4*)(h1 + (size_t)s2*KP_GCN + f0);
            f16x4 v3 = *(const f16x4*)(h1 + (size_t)s3*KP_GCN + f0);
            a0 += n0*(float)v0.x + n1*(float)v1.x + n2*(float)v2.x + n3*(float)v3.x;
            a1 += n0*(float)v0.y + n1*(float)v1.y + n2*(float)v2.y + n3*(float)v3.y;
            a2 += n0*(float)v0.z + n1*(float)v1.z + n2*(float)v2.z + n3*(float)v3.z;
            a3 += n0*(float)v0.w + n1*(float)v1.w + n2*(float)v2.w + n3*(float)v3.w;
        }
        for (; s < e; s++){
            int s0 = src_sorted[s];
            float n0 = dinv[s0];
            f16x4 v0 = *(const f16x4*)(h1 + (size_t)s0*KP_GCN + f0);
            a0 += n0*(float)v0.x;
            a1 += n0*(float)v0.y;
            a2 += n0*(float)v0.z;
            a3 += n0*(float)v0.w;
        }
        float dn = dinv[n];
        f16x4 r;
        r.x = (half_t)(dn*a0); r.y = (half_t)(dn*a1);
        r.z = (half_t)(dn*a2); r.w = (half_t)(dn*a3);
        *(f16x4*)(agg + (size_t)n*KP_GCN + f0) = r;
    } else if (t < 176){
        f16x4 z = {(half_t)0.f,(half_t)0.f,(half_t)0.f,(half_t)0.f};
        *(f16x4*)(agg + (size_t)n*KP_GCN + f0) = z;
    }
}

/* ---------------- fused tail MLP: 64->32->16->1 ---------------- */
__global__ __launch_bounds__(256)
void k_tail(const half_t* __restrict__ h4,
            const float* __restrict__ Wfc1, const float* __restrict__ bfc1,
            const float* __restrict__ Wfc2, const float* __restrict__ bfc2,
            const float* __restrict__ Wout, const float* __restrict__ bout,
            float* __restrict__ out){
    __shared__ float W1[64*32];
    __shared__ float W2[32*16];
    __shared__ float Wo[16];
    __shared__ float b1[32];
    __shared__ float b2[16];
    __shared__ float r1[8][32];
    __shared__ float r2[8][16];
    int tid = threadIdx.x;
    for (int i = tid; i < 64*32; i += 256) W1[i] = Wfc1[i];
    for (int i = tid; i < 32*16; i += 256) W2[i] = Wfc2[i];
    if (tid < 16) Wo[tid] = Wout[tid];
    if (tid < 32) b1[tid] = bfc1[tid];
    if (tid < 16) b2[tid] = bfc2[tid];
    __syncthreads();
    int g = tid >> 5, j = tid & 31;
    int node = blockIdx.x*8 + g;
    const half_t* hr = h4 + (size_t)node*F_G2;
    float acc = 0.f;
    #pragma unroll 8
    for (int i = 0; i < 64; i++) acc += (float)hr[i]*W1[i*32 + j];
    r1[g][j] = lky(acc + b1[j], 0.01f);
    __syncthreads();
    if (j < 16){
        float a2 = 0.f;
        #pragma unroll
        for (int i = 0; i < 32; i++) a2 += r1[g][i]*W2[i*16 + j];
        r2[g][j] = lky(a2 + b2[j], 0.01f);
    }
    __syncthreads();
    if (j == 0){
        float a3 = 0.f;
        #pragma unroll
        for (int i = 0; i < 16; i++) a3 += r2[g][i]*Wo[i];
        out[node] = a3 + bout[0];
    }
}

/* ---------------- launch ---------------- */

extern "C" void kernel_launch(void* const* d_in, const int* in_sizes, int n_in,
                              void* d_out, int out_size, void* d_ws, size_t ws_size,
                              hipStream_t stream){
    const float* x       = (const float*)d_in[0];
    const int*   ei      = (const int*)  d_in[1];
    const float* W_gat   = (const float*)d_in[2];
    const float* att_src = (const float*)d_in[3];
    const float* att_dst = (const float*)d_in[4];
    const float* b_gat   = (const float*)d_in[5];
    const float* W_gcn   = (const float*)d_in[6];
    const float* b_gcn   = (const float*)d_in[7];
    const float* W_g1    = (const float*)d_in[8];
    const float* b_g1    = (const float*)d_in[9];
    const float* W_g2    = (const float*)d_in[10];
    const float* b_g2    = (const float*)d_in[11];
    const float* W_fc1   = (const float*)d_in[12];
    const float* b_fc1   = (const float*)d_in[13];
    const float* W_fc2   = (const float*)d_in[14];
    const float* b_fc2   = (const float*)d_in[15];
    const float* W_out   = (const float*)d_in[16];
    const float* b_out   = (const float*)d_in[17];
    float* out = (float*)d_out;
    char* ws = (char*)d_ws;

    size_t off = 0;
    auto alloc = [&](size_t bytes){ size_t o = off; off += (bytes + 255) & ~(size_t)255; return o; };
    size_t o_counts = alloc(N_NODES*4);
    size_t o_cursor = alloc(N_NODES*4);
    size_t o_offs   = alloc((N_NODES+1)*4);
    size_t o_as     = alloc(N_NODES*HEADS*4);
    size_t o_ad     = alloc(N_NODES*HEADS*4);
    size_t o_invs   = alloc(N_NODES*HEADS*4);
    size_t o_dinv   = alloc(N_NODES*4);
    size_t o_srcs   = alloc(E_TOT*4);
    size_t o_esrt   = alloc((size_t)E_TOT*HEADS*4);
    size_t o_xh     = alloc((size_t)MPAD*KP_GAT*2);
    size_t o_xt     = alloc((size_t)MPAD*NP_GAT*2);
    size_t o_h1     = alloc((size_t)N_NODES*KP_GCN*2);
    size_t o_agg    = alloc((size_t)MPAD*KP_GCN*2);
    size_t o_h2     = alloc((size_t)MPAD*KP_G1*2);
    size_t o_h3     = alloc((size_t)MPAD*KP_G2*2);
    size_t o_h4     = alloc((size_t)MPAD*F_G2*2);
    size_t o_wgatT  = alloc((size_t)NP_GAT*KP_GAT*2);
    size_t o_wgcnT  = alloc((size_t)NP_GCN*KP_GCN*2);
    size_t o_wg1T   = alloc((size_t)NP_G1*KP_G1*2);
    size_t o_wg2T   = alloc((size_t)NP_G2*KP_G2*2);

    int*    counts  = (int*)(ws + o_counts);
    int*    cursor  = (int*)(ws + o_cursor);
    int*    offsets = (int*)(ws + o_offs);
    float*  a_s     = (float*)(ws + o_as);
    float*  a_d     = (float*)(ws + o_ad);
    float*  inv_s   = (float*)(ws + o_invs);
    float*  dinv    = (float*)(ws + o_dinv);
    int*    src_srt = (int*)(ws + o_srcs);
    float*  e_srt   = (float*)(ws + o_esrt);
    half_t* xh      = (half_t*)(ws + o_xh);
    half_t* xt_h    = (half_t*)(ws + o_xt);
    half_t* h1h     = (half_t*)(ws + o_h1);
    half_t* aggh    = (half_t*)(ws + o_agg);
    half_t* h2h     = (half_t*)(ws + o_h2);
    half_t* h3h     = (half_t*)(ws + o_h3);
    half_t* h4h     = (half_t*)(ws + o_h4);
    half_t* WgatT   = (half_t*)(ws + o_wgatT);
    half_t* WgcnT   = (half_t*)(ws + o_wgcnT);
    half_t* Wg1T    = (half_t*)(ws + o_wg1T);
    half_t* Wg2T    = (half_t*)(ws + o_wg2T);

    /* CSR build (counts+cursor adjacent: one memset covers both) */
    hipMemsetAsync(ws + o_counts, 0, o_offs - o_counts, stream);
    k_count<<<(E_TOT+255)/256, 256, 0, stream>>>(ei, counts);
    k_scan<<<1, 1024, 0, stream>>>(counts, offsets, dinv);
    k_fill<<<(E_TOT+255)/256, 256, 0, stream>>>(ei, offsets, cursor, src_srt);

    /* fused fp16 packing (one launch, y-sliced) */
    k_packy<<<dim3(PACK_BX, 5), 256, 0, stream>>>(x, W_gat, W_gcn, W_g1, W_g2,
                                                  xh, WgatT, WgcnT, Wg1T, Wg2T);

    /* GAT: xt = x @ W_gat */
    k_hgemm<<<dim3(NP_GAT/64, MPAD/128), 256, 0, stream>>>(
        xh, WgatT, xt_h, nullptr, F_GAT, NP_GAT, KP_GAT, 1.0f);
    k_attn_ad<<<(N_NODES*HEADS+255)/256, 256, 0, stream>>>(xt_h, att_src, att_dst, a_s, a_d);
    k_softmax<<<(N_NODES*HEADS+255)/256, 256, 0, stream>>>(offsets, src_srt, a_s, a_d, e_srt, inv_s);
    k_gat_agg<<<N_NODES, 192, 0, stream>>>(offsets, src_srt, e_srt, inv_s, xt_h, b_gat, h1h);

    /* GCN aggregate-first */
    k_gcn_pre<<<N_NODES, 192, 0, stream>>>(offsets, src_srt, dinv, h1h, aggh);
    k_hgemm<<<dim3(NP_GCN/64, MPAD/128), 256, 0, stream>>>(
        aggh, WgcnT, h2h, b_gcn, F_GCN, KP_G1, KP_GCN, 0.01f);

    /* dense tail */
    k_hgemm<<<dim3(NP_G1/64, MPAD/128), 256, 0, stream>>>(
        h2h, Wg1T, h3h, b_g1, F_G1, KP_G2, KP_G1, 0.01f);
    k_hgemm<<<dim3(NP_G2/64, MPAD/128), 256, 0, stream>>>(
        h3h, Wg2T, h4h, b_g2, F_G2, F_G2, KP_G2, 0.01f);
    k_tail<<<N_NODES/8, 256, 0, stream>>>(h4h, W_fc1, b_fc1, W_fc2, b_fc2,
                                          W_out, b_out, out);
}